// Round 1
// baseline (705.612 us; speedup 1.0000x reference)
//
#include <hip/hip_runtime.h>
#include <cstdint>

#define BATCH 128
#define NODES 1023
#define LEAVES 512
#define IN_DIM 300
#define MEM 300
#define NP 320              // padded per-set N (and per-child K)
#define OUT_HALF (BATCH*MEM)

typedef __bf16   bf16x8 __attribute__((ext_vector_type(8)));
typedef short    s16x8  __attribute__((ext_vector_type(8)));
typedef short    s16x4  __attribute__((ext_vector_type(4)));
typedef float    f32x4  __attribute__((ext_vector_type(4)));
typedef _Float16 half_t;

__device__ __forceinline__ short f2bf(float f) {
    unsigned u = __float_as_uint(f);
    u += 0x7fff + ((u >> 16) & 1);
    return (short)(u >> 16);
}
__device__ __forceinline__ float sigf(float x)  { return 1.0f / (1.0f + __expf(-x)); }
__device__ __forceinline__ float tanhf_(float x){ return 1.0f - 2.0f / (1.0f + __expf(2.0f * x)); }

__device__ __forceinline__ f32x4 mfma16(s16x8 a, s16x8 b, f32x4 c) {
    return __builtin_amdgcn_mfma_f32_16x16x32_bf16(
        __builtin_bit_cast(bf16x8, a), __builtin_bit_cast(bf16x8, b), c, 0, 0, 0);
}

// async 16B/lane global->LDS: lds dst = wave-uniform base + lane*16
__device__ __forceinline__ void dma16(const short* src, short* ldsBase) {
    __builtin_amdgcn_global_load_lds(
        (const __attribute__((address_space(1))) unsigned int*)src,
        (__attribute__((address_space(3))) unsigned int*)ldsBase,
        16, 0, 0);
}

// ---------- weight packing: B-fragment order ----------
// frag-block (kb,s,nb): 64 lanes x 8 bf16; lane l holds B[k=kb*32+(l>>4)*8+j][n=nb*16+(l&15)]
__global__ __launch_bounds__(256) void pack_node_w(
    const float* __restrict__ Wiouh, const float* __restrict__ Wfh, short* __restrict__ Wpk)
{
    int gid = blockIdx.x * 256 + threadIdx.x;           // 2000 frags * 64 lanes
    if (gid >= 2000 * 64) return;
    int fb = gid >> 6, l = gid & 63;
    int kb = fb / 100, rem = fb % 100, s = rem / 20, nb = rem % 20;
    int n = nb * 16 + (l & 15);
    int kbase = kb * 32 + (l >> 4) * 8;                 // k' in [0,640)
    short v[8];
#pragma unroll
    for (int j = 0; j < 8; ++j) {
        int kp = kbase + j;
        int side = kp >= NP;
        int kk = kp - side * NP;
        float f = 0.0f;
        if (kk < MEM && n < MEM) {
            int k = side * MEM + kk;
            f = (s < 3) ? Wiouh[(size_t)k * 900 + s * 300 + n]
                        : Wfh[(size_t)k * 600 + (s - 3) * 300 + n];
        }
        v[j] = f2bf(f);
    }
    *(s16x8*)&Wpk[(size_t)gid * 8] = *(s16x8*)v;
}

__global__ __launch_bounds__(256) void pack_leaf_w(
    const float* __restrict__ Wfioux, short* __restrict__ Wpk)
{
    int gid = blockIdx.x * 256 + threadIdx.x;           // 600 frags * 64 lanes
    if (gid >= 600 * 64) return;
    int fb = gid >> 6, l = gid & 63;
    int kb = fb / 60, rem = fb % 60, s = rem / 20, nb = rem % 20;
    int n = nb * 16 + (l & 15);
    int kbase = kb * 32 + (l >> 4) * 8;                 // k' in [0,320)
    short v[8];
#pragma unroll
    for (int j = 0; j < 8; ++j) {
        int kp = kbase + j;
        float f = 0.0f;
        if (kp < IN_DIM && n < MEM)
            f = Wfioux[(size_t)kp * 1200 + (s + 1) * 300 + n];
        v[j] = f2bf(f);
    }
    *(s16x8*)&Wpk[(size_t)gid * 8] = *(s16x8*)v;
}

// ---------- leaf-input packing: X[leaf][b][kp] bf16, kp padded to 320 ----------
__global__ __launch_bounds__(256) void pack_x(
    const float* __restrict__ inputs, short* __restrict__ X)
{
    int gid = blockIdx.x * 256 + threadIdx.x;           // 512*128*80 quads
    if (gid >= LEAVES * BATCH * (NP / 4)) return;
    int q = gid % (NP / 4);
    int rb = gid / (NP / 4);
    int b = rb % BATCH, leaf = rb / BATCH;
    short v[4] = {0, 0, 0, 0};
    if (q < IN_DIM / 4) {
        f32x4 f = *(const f32x4*)&inputs[((size_t)b * NODES + leaf) * IN_DIM + q * 4];
        v[0] = f2bf(f[0]); v[1] = f2bf(f[1]); v[2] = f2bf(f[2]); v[3] = f2bf(f[3]);
    }
    *(s16x4*)&X[(size_t)gid * 4] = *(s16x4*)v;
}

// ---------- leaf GEMM+gates: block = 1 leaf x 64-col group ----------
// Double-buffered weight staging: STAGE(kb+1) + A-reg prefetch issued BEFORE
// the MFMAs on buffer kb; single barrier per K-step (its implicit vmcnt(0)
// drain lands after the compute, so DMA latency overlaps the MFMAs).
__global__ __launch_bounds__(256, 3) void leaf_mfma(
    const short* __restrict__ X, const short* __restrict__ Wpk,
    const float* __restrict__ b_fioux, half_t* __restrict__ C, short* __restrict__ H)
{
    __shared__ short Bs[2][12 * 512];                   // 2 x 12 frags x 1KB
    const int t = threadIdx.x;
    const int l = t & 63, w = t >> 6;                   // 4 waves, w = row-group
    const int lane16 = l & 15, quad = l >> 4;
    const int leaf = blockIdx.x;
    const int y = blockIdx.y;                           // 64-col group 0..4

    const short* Xb = X + (size_t)leaf * BATCH * NP;

    f32x4 acc[3][4][2];                                 // [set][frag][row-half]
#pragma unroll
    for (int s = 0; s < 3; ++s)
#pragma unroll
        for (int f = 0; f < 4; ++f)
#pragma unroll
            for (int mi = 0; mi < 2; ++mi) acc[s][f][mi] = (f32x4)(0.0f);

    auto stage = [&](int kb, int buf) {
#pragma unroll
        for (int fl = w; fl < 12; fl += 4) {            // 3 frags per wave
            int s = fl >> 2, f = fl & 3;
            const short* src = Wpk + ((size_t)((kb * 3 + s) * 20 + y * 4 + f) * 64 + l) * 8;
            dma16(src, &Bs[buf][fl * 512]);
        }
    };
    auto aload = [&](int kb, s16x8 (&a)[2]) {
        const int koff = kb * 32 + quad * 8;
        a[0] = *(const s16x8*)(Xb + (size_t)(w * 32 + lane16) * NP + koff);
        a[1] = *(const s16x8*)(Xb + (size_t)(w * 32 + 16 + lane16) * NP + koff);
    };

    s16x8 aC[2], aN[2];
    stage(0, 0);
    aload(0, aC);
    __syncthreads();

#pragma unroll
    for (int kb = 0; kb < 10; ++kb) {
        const int buf = kb & 1;
        if (kb < 9) { stage(kb + 1, buf ^ 1); aload(kb + 1, aN); }
#pragma unroll
        for (int s = 0; s < 3; ++s)
#pragma unroll
            for (int f = 0; f < 4; ++f) {
                s16x8 b = *(const s16x8*)&Bs[buf][(s * 4 + f) * 512 + l * 8];
                acc[s][f][0] = mfma16(aC[0], b, acc[s][f][0]);
                acc[s][f][1] = mfma16(aC[1], b, acc[s][f][1]);
            }
        __syncthreads();
        aC[0] = aN[0]; aC[1] = aN[1];
    }

#pragma unroll
    for (int f = 0; f < 4; ++f) {
        const int col = y * 64 + f * 16 + lane16;
        const bool valid = col < MEM;
        float bi = 0, bo = 0, bu = 0;
        if (valid) { bi = b_fioux[300 + col]; bo = b_fioux[600 + col]; bu = b_fioux[900 + col]; }
#pragma unroll
        for (int mi = 0; mi < 2; ++mi)
#pragma unroll
            for (int r = 0; r < 4; ++r) {
                int b = w * 32 + mi * 16 + quad * 4 + r;
                size_t hIdx = ((size_t)leaf * BATCH + b) * NP + col;
                if (valid) {
                    float ig = sigf(acc[0][f][mi][r] + bi);
                    float og = sigf(acc[1][f][mi][r] + bo);
                    float ug = tanhf_(acc[2][f][mi][r] + bu);
                    float c = ig * ug;
                    float h = og * tanhf_(c);
                    C[((size_t)leaf * BATCH + b) * MEM + col] = (half_t)c;
                    H[hIdx] = f2bf(h);
                } else {
                    H[hIdx] = 0;
                }
            }
    }
}

// ---------- internal node GEMM+gates: block = 1 node x 32-col group ----------
// K-step widened 32->64 (20 frags/step, 10 steps over K'=640), double-buffered
// weight LDS + A-reg prefetch, ONE barrier per step.
__global__ __launch_bounds__(256, 3) void node_mfma(
    const short* __restrict__ Wpk, const float* __restrict__ b_fioux,
    const int* __restrict__ left_idx, const int* __restrict__ right_idx,
    half_t* __restrict__ C, short* __restrict__ H,
    int level_start, float* __restrict__ out)
{
    __shared__ short Bs[2][20 * 512];                   // 2 x 20 frags x 1KB
    const int t = threadIdx.x;
    const int l = t & 63, w = t >> 6;                   // 4 waves, w = row-group
    const int lane16 = l & 15, quad = l >> 4;
    const int node = level_start + blockIdx.x;
    const int y = blockIdx.y;                           // 32-col group 0..9

    const int li = left_idx[node], ri = right_idx[node];
    const short* HL = H + (size_t)li * BATCH * NP;
    const short* HR = H + (size_t)ri * BATCH * NP;

    f32x4 acc[5][2][2];                                 // [set][frag][row-half]
#pragma unroll
    for (int s = 0; s < 5; ++s)
#pragma unroll
        for (int f = 0; f < 2; ++f)
#pragma unroll
            for (int mi = 0; mi < 2; ++mi) acc[s][f][mi] = (f32x4)(0.0f);

    // frag layout in LDS buffer: fl = ksub*10 + s*2 + f  (ksub = which 32-K half)
    auto stage = [&](int st, int buf) {
#pragma unroll
        for (int fl = w; fl < 20; fl += 4) {            // 5 frags per wave
            int ksub = fl / 10, rem = fl - ksub * 10;
            int s = rem >> 1, f = rem & 1;
            int kb32 = st * 2 + ksub;
            const short* src = Wpk + ((size_t)((kb32 * 5 + s) * 20 + y * 2 + f) * 64 + l) * 8;
            dma16(src, &Bs[buf][fl * 512]);
        }
    };
    auto aload = [&](int st, s16x8 (&a)[2][2]) {
        const int side = st >= 5;
        const short* Hb = (side ? HR : HL) + (st - side * 5) * 64 + quad * 8;
#pragma unroll
        for (int ksub = 0; ksub < 2; ++ksub) {
            a[ksub][0] = *(const s16x8*)(Hb + (size_t)(w * 32 + lane16) * NP + ksub * 32);
            a[ksub][1] = *(const s16x8*)(Hb + (size_t)(w * 32 + 16 + lane16) * NP + ksub * 32);
        }
    };

    s16x8 aC[2][2], aN[2][2];
    stage(0, 0);
    aload(0, aC);
    __syncthreads();

#pragma unroll
    for (int st = 0; st < 10; ++st) {
        const int buf = st & 1;
        if (st < 9) { stage(st + 1, buf ^ 1); aload(st + 1, aN); }
#pragma unroll
        for (int ksub = 0; ksub < 2; ++ksub)
#pragma unroll
            for (int s = 0; s < 5; ++s)
#pragma unroll
                for (int f = 0; f < 2; ++f) {
                    s16x8 b = *(const s16x8*)&Bs[buf][(ksub * 10 + s * 2 + f) * 512 + l * 8];
                    acc[s][f][0] = mfma16(aC[ksub][0], b, acc[s][f][0]);
                    acc[s][f][1] = mfma16(aC[ksub][1], b, acc[s][f][1]);
                }
        __syncthreads();
#pragma unroll
        for (int i = 0; i < 2; ++i) { aC[i][0] = aN[i][0]; aC[i][1] = aN[i][1]; }
    }

#pragma unroll
    for (int f = 0; f < 2; ++f) {
        const int col = y * 32 + f * 16 + lane16;
        const bool valid = col < MEM;
        float bff = 0, bi = 0, bo = 0, bu = 0;
        if (valid) {
            bff = b_fioux[col]; bi = b_fioux[300 + col];
            bo = b_fioux[600 + col]; bu = b_fioux[900 + col];
        }
#pragma unroll
        for (int mi = 0; mi < 2; ++mi)
#pragma unroll
            for (int r = 0; r < 4; ++r) {
                int row = w * 32 + mi * 16 + quad * 4 + r;
                size_t hIdx = ((size_t)node * BATCH + row) * NP + col;
                if (valid) {
                    float cl = (float)C[((size_t)li * BATCH + row) * MEM + col];
                    float cr = (float)C[((size_t)ri * BATCH + row) * MEM + col];
                    float ig = sigf(acc[0][f][mi][r] + bi);
                    float og = sigf(acc[1][f][mi][r] + bo);
                    float ug = tanhf_(acc[2][f][mi][r] + bu);
                    float fl = sigf(acc[3][f][mi][r] + bff);
                    float fr = sigf(acc[4][f][mi][r] + bff);
                    float c = ig * ug + fl * cl + fr * cr;
                    float h = og * tanhf_(c);
                    C[((size_t)node * BATCH + row) * MEM + col] = (half_t)c;
                    H[hIdx] = f2bf(h);
                    if (out) {
                        out[row * MEM + col] = c;
                        out[OUT_HALF + row * MEM + col] = h;
                    }
                } else {
                    H[hIdx] = 0;
                }
            }
    }
}

extern "C" void kernel_launch(void* const* d_in, const int* in_sizes, int n_in,
                              void* d_out, int out_size, void* d_ws, size_t ws_size,
                              hipStream_t stream) {
    const float* inputs  = (const float*)d_in[0];
    const float* Wfioux  = (const float*)d_in[1];
    const float* b_fioux = (const float*)d_in[2];
    const float* Wiouh   = (const float*)d_in[3];
    const float* Wfh     = (const float*)d_in[4];
    const int*   left_idx  = (const int*)d_in[5];
    const int*   right_idx = (const int*)d_in[6];

    half_t* C   = (half_t*)d_ws;                              // [1023][128][300] fp16
    short*  H   = (short*)(C + (size_t)NODES * BATCH * MEM);  // [1023][128][320] bf16
    short* WpkN = H + (size_t)NODES * BATCH * NP;             // 2000 frag-blocks
    short* WpkL = WpkN + (size_t)2000 * 512;                  // 600 frag-blocks
    short* X    = WpkL + (size_t)600 * 512;                   // [512][128][320] bf16
    float* out  = (float*)d_out;

    pack_x<<<(LEAVES * BATCH * (NP / 4) + 255) / 256, 256, 0, stream>>>(inputs, X);
    pack_leaf_w<<<150, 256, 0, stream>>>(Wfioux, WpkL);
    pack_node_w<<<500, 256, 0, stream>>>(Wiouh, Wfh, WpkN);

    leaf_mfma<<<dim3(LEAVES, 5), 256, 0, stream>>>(X, WpkL, b_fioux, C, H);

    static const int starts[9] = {512, 768, 896, 960, 992, 1008, 1016, 1020, 1022};
    static const int sizes [9] = {256, 128,  64,  32,  16,    8,    4,    2,    1};
    for (int lvl = 0; lvl < 9; ++lvl) {
        bool root = (lvl == 8);
        node_mfma<<<dim3(sizes[lvl], 10), 256, 0, stream>>>(
            WpkN, b_fioux, left_idx, right_idx, C, H, starts[lvl],
            root ? out : nullptr);
    }
}

// Round 2
// 654.608 us; speedup vs baseline: 1.0779x; 1.0779x over previous
//
#include <hip/hip_runtime.h>
#include <cstdint>

#define BATCH 128
#define NODES 1023
#define LEAVES 512
#define IN_DIM 300
#define MEM 300
#define NP 320              // padded per-set N (and per-child K)
#define OUT_HALF (BATCH*MEM)

typedef __bf16   bf16x8 __attribute__((ext_vector_type(8)));
typedef short    s16x8  __attribute__((ext_vector_type(8)));
typedef short    s16x4  __attribute__((ext_vector_type(4)));
typedef float    f32x4  __attribute__((ext_vector_type(4)));
typedef _Float16 half_t;

__device__ __forceinline__ short f2bf(float f) {
    unsigned u = __float_as_uint(f);
    u += 0x7fff + ((u >> 16) & 1);
    return (short)(u >> 16);
}
__device__ __forceinline__ float sigf(float x)  { return 1.0f / (1.0f + __expf(-x)); }
__device__ __forceinline__ float tanhf_(float x){ return 1.0f - 2.0f / (1.0f + __expf(2.0f * x)); }

__device__ __forceinline__ f32x4 mfma16(s16x8 a, s16x8 b, f32x4 c) {
    return __builtin_amdgcn_mfma_f32_16x16x32_bf16(
        __builtin_bit_cast(bf16x8, a), __builtin_bit_cast(bf16x8, b), c, 0, 0, 0);
}

// async 16B/lane global->LDS: lds dst = wave-uniform base + lane*16
__device__ __forceinline__ void dma16(const short* src, short* ldsBase) {
    __builtin_amdgcn_global_load_lds(
        (const __attribute__((address_space(1))) unsigned int*)src,
        (__attribute__((address_space(3))) unsigned int*)ldsBase,
        16, 0, 0);
}

// ---------- weight packing: B-fragment order ----------
// frag-block (kb,s,nb): 64 lanes x 8 bf16; lane l holds B[k=kb*32+(l>>4)*8+j][n=nb*16+(l&15)]
__global__ __launch_bounds__(256) void pack_node_w(
    const float* __restrict__ Wiouh, const float* __restrict__ Wfh, short* __restrict__ Wpk)
{
    int gid = blockIdx.x * 256 + threadIdx.x;           // 2000 frags * 64 lanes
    if (gid >= 2000 * 64) return;
    int fb = gid >> 6, l = gid & 63;
    int kb = fb / 100, rem = fb % 100, s = rem / 20, nb = rem % 20;
    int n = nb * 16 + (l & 15);
    int kbase = kb * 32 + (l >> 4) * 8;                 // k' in [0,640)
    short v[8];
#pragma unroll
    for (int j = 0; j < 8; ++j) {
        int kp = kbase + j;
        int side = kp >= NP;
        int kk = kp - side * NP;
        float f = 0.0f;
        if (kk < MEM && n < MEM) {
            int k = side * MEM + kk;
            f = (s < 3) ? Wiouh[(size_t)k * 900 + s * 300 + n]
                        : Wfh[(size_t)k * 600 + (s - 3) * 300 + n];
        }
        v[j] = f2bf(f);
    }
    *(s16x8*)&Wpk[(size_t)gid * 8] = *(s16x8*)v;
}

__global__ __launch_bounds__(256) void pack_leaf_w(
    const float* __restrict__ Wfioux, short* __restrict__ Wpk)
{
    int gid = blockIdx.x * 256 + threadIdx.x;           // 600 frags * 64 lanes
    if (gid >= 600 * 64) return;
    int fb = gid >> 6, l = gid & 63;
    int kb = fb / 60, rem = fb % 60, s = rem / 20, nb = rem % 20;
    int n = nb * 16 + (l & 15);
    int kbase = kb * 32 + (l >> 4) * 8;                 // k' in [0,320)
    short v[8];
#pragma unroll
    for (int j = 0; j < 8; ++j) {
        int kp = kbase + j;
        float f = 0.0f;
        if (kp < IN_DIM && n < MEM)
            f = Wfioux[(size_t)kp * 1200 + (s + 1) * 300 + n];
        v[j] = f2bf(f);
    }
    *(s16x8*)&Wpk[(size_t)gid * 8] = *(s16x8*)v;
}

// ---------- leaf-input packing: X[leaf][b][kp] bf16, kp padded to 320 ----------
__global__ __launch_bounds__(256) void pack_x(
    const float* __restrict__ inputs, short* __restrict__ X)
{
    int gid = blockIdx.x * 256 + threadIdx.x;           // 512*128*80 quads
    if (gid >= LEAVES * BATCH * (NP / 4)) return;
    int q = gid % (NP / 4);
    int rb = gid / (NP / 4);
    int b = rb % BATCH, leaf = rb / BATCH;
    short v[4] = {0, 0, 0, 0};
    if (q < IN_DIM / 4) {
        f32x4 f = *(const f32x4*)&inputs[((size_t)b * NODES + leaf) * IN_DIM + q * 4];
        v[0] = f2bf(f[0]); v[1] = f2bf(f[1]); v[2] = f2bf(f[2]); v[3] = f2bf(f[3]);
    }
    *(s16x4*)&X[(size_t)gid * 4] = *(s16x4*)v;
}

// ---------- leaf GEMM+gates: block = 1 leaf x 64-col group ----------
// T3+T4 pipeline: 4-buffer LDS ring, depth-3 prefetch, raw s_barrier with
// counted s_waitcnt vmcnt(N) BEFORE the barrier (never 0 in steady state).
// Per wave per step: 3 dma16 + 2 A-loads = 5 vmem ops -> steady wait = vmcnt(10).
__global__ __launch_bounds__(256, 3) void leaf_mfma(
    const short* __restrict__ X, const short* __restrict__ Wpk,
    const float* __restrict__ b_fioux, half_t* __restrict__ C, short* __restrict__ H)
{
    __shared__ short Bs[4][12 * 512];                   // 4 ring bufs x 12 frags x 1KB
    const int t = threadIdx.x;
    const int l = t & 63, w = t >> 6;                   // 4 waves, w = row-group
    const int lane16 = l & 15, quad = l >> 4;
    const int leaf = blockIdx.x;
    const int y = blockIdx.y;                           // 64-col group 0..4

    const short* Xb = X + (size_t)leaf * BATCH * NP;

    f32x4 acc[3][4][2];                                 // [set][frag][row-half]
#pragma unroll
    for (int s = 0; s < 3; ++s)
#pragma unroll
        for (int f = 0; f < 4; ++f)
#pragma unroll
            for (int mi = 0; mi < 2; ++mi) acc[s][f][mi] = (f32x4)(0.0f);

    s16x8 A[4][2];                                      // A-fragment ring (static idx only)

#define L_STAGE(KB, BUF) do {                                                    \
    _Pragma("unroll")                                                            \
    for (int fl = w; fl < 12; fl += 4) {                                         \
        int s_ = fl >> 2, f_ = fl & 3;                                           \
        const short* src_ = Wpk +                                                \
            ((size_t)(((KB) * 3 + s_) * 20 + y * 4 + f_) * 64 + l) * 8;          \
        dma16(src_, &Bs[BUF][fl * 512]);                                         \
    } } while (0)

#define L_ALOAD(KB, SLOT) do {                                                   \
    const int koff_ = (KB) * 32 + quad * 8;                                      \
    A[SLOT][0] = *(const s16x8*)(Xb + (size_t)(w * 32 + lane16) * NP + koff_);   \
    A[SLOT][1] = *(const s16x8*)(Xb + (size_t)(w * 32 + 16 + lane16) * NP + koff_); \
} while (0)

    // prologue: issue steps 0,1,2 (15 vmem ops per wave in flight)
    L_STAGE(0, 0); L_ALOAD(0, 0);
    L_STAGE(1, 1); L_ALOAD(1, 1);
    L_STAGE(2, 2); L_ALOAD(2, 2);

// waitcnt BEFORE barrier: guarantees every wave's step-ST stage is complete when
// any wave crosses. issue AFTER barrier: ring distance 3 makes the WAR on buffer
// (ST+3)&3 == (ST-1)&3 safe (its readers finished before this barrier).
#define L_STEP(ST, WAITN) do {                                                   \
    asm volatile("s_waitcnt vmcnt(" #WAITN ")" ::: "memory");                    \
    __builtin_amdgcn_s_barrier();                                                \
    asm volatile("" ::: "memory");                                               \
    if ((ST) + 3 < 10) { L_STAGE((ST) + 3, ((ST) + 3) & 3);                      \
                         L_ALOAD((ST) + 3, ((ST) + 3) & 3); }                    \
    _Pragma("unroll")                                                            \
    for (int s_ = 0; s_ < 3; ++s_) {                                             \
        _Pragma("unroll")                                                        \
        for (int f_ = 0; f_ < 4; ++f_) {                                         \
            s16x8 b_ = *(const s16x8*)&Bs[(ST) & 3][(s_ * 4 + f_) * 512 + l * 8];\
            acc[s_][f_][0] = mfma16(A[(ST) & 3][0], b_, acc[s_][f_][0]);         \
            acc[s_][f_][1] = mfma16(A[(ST) & 3][1], b_, acc[s_][f_][1]);         \
        }                                                                        \
    } } while (0)

    L_STEP(0, 10); L_STEP(1, 10); L_STEP(2, 10); L_STEP(3, 10); L_STEP(4, 10);
    L_STEP(5, 10); L_STEP(6, 10); L_STEP(7, 10); L_STEP(8, 5);  L_STEP(9, 0);

#undef L_STEP
#undef L_ALOAD
#undef L_STAGE

#pragma unroll
    for (int f = 0; f < 4; ++f) {
        const int col = y * 64 + f * 16 + lane16;
        const bool valid = col < MEM;
        float bi = 0, bo = 0, bu = 0;
        if (valid) { bi = b_fioux[300 + col]; bo = b_fioux[600 + col]; bu = b_fioux[900 + col]; }
#pragma unroll
        for (int mi = 0; mi < 2; ++mi)
#pragma unroll
            for (int r = 0; r < 4; ++r) {
                int b = w * 32 + mi * 16 + quad * 4 + r;
                size_t hIdx = ((size_t)leaf * BATCH + b) * NP + col;
                if (valid) {
                    float ig = sigf(acc[0][f][mi][r] + bi);
                    float og = sigf(acc[1][f][mi][r] + bo);
                    float ug = tanhf_(acc[2][f][mi][r] + bu);
                    float c = ig * ug;
                    float h = og * tanhf_(c);
                    C[((size_t)leaf * BATCH + b) * MEM + col] = (half_t)c;
                    H[hIdx] = f2bf(h);
                } else {
                    H[hIdx] = 0;
                }
            }
    }
}

// ---------- internal node GEMM+gates: block = 1 node x 32-col group ----------
// Same T3+T4 pipeline, K-step 32 (20 steps over K'=640). Staging padded to 12
// frags/step (slots 10,11 are benign duplicates) so every wave issues exactly
// 3 dma16 + 2 A-loads per step -> uniform compile-time vmcnt counts.
__global__ __launch_bounds__(256, 3) void node_mfma(
    const short* __restrict__ Wpk, const float* __restrict__ b_fioux,
    const int* __restrict__ left_idx, const int* __restrict__ right_idx,
    half_t* __restrict__ C, short* __restrict__ H,
    int level_start, float* __restrict__ out)
{
    __shared__ short Bs[4][12 * 512];                   // 4 ring bufs x 12KB
    const int t = threadIdx.x;
    const int l = t & 63, w = t >> 6;                   // 4 waves, w = row-group
    const int lane16 = l & 15, quad = l >> 4;
    const int node = level_start + blockIdx.x;
    const int y = blockIdx.y;                           // 32-col group 0..9

    const int li = left_idx[node], ri = right_idx[node];
    const short* HL = H + (size_t)li * BATCH * NP;
    const short* HR = H + (size_t)ri * BATCH * NP;

    f32x4 acc[5][2][2];                                 // [set][frag][row-half]
#pragma unroll
    for (int s = 0; s < 5; ++s)
#pragma unroll
        for (int f = 0; f < 2; ++f)
#pragma unroll
            for (int mi = 0; mi < 2; ++mi) acc[s][f][mi] = (f32x4)(0.0f);

    s16x8 A[4][2];

#define N_STAGE(KB, BUF) do {                                                    \
    _Pragma("unroll")                                                            \
    for (int fl = w; fl < 12; fl += 4) {                                         \
        int rfl_ = (fl < 10) ? fl : fl - 10;            /* slots 10,11: dup */   \
        int s_ = rfl_ >> 1, f_ = rfl_ & 1;                                       \
        const short* src_ = Wpk +                                                \
            ((size_t)(((KB) * 5 + s_) * 20 + y * 2 + f_) * 64 + l) * 8;          \
        dma16(src_, &Bs[BUF][fl * 512]);                                         \
    } } while (0)

#define N_ALOAD(KB, SLOT) do {                                                   \
    const short* Hb_ = (((KB) >= 10) ? HR : HL) +                                \
                       ((KB) - (((KB) >= 10) ? 10 : 0)) * 32 + quad * 8;         \
    A[SLOT][0] = *(const s16x8*)(Hb_ + (size_t)(w * 32 + lane16) * NP);          \
    A[SLOT][1] = *(const s16x8*)(Hb_ + (size_t)(w * 32 + 16 + lane16) * NP);     \
} while (0)

    N_STAGE(0, 0); N_ALOAD(0, 0);
    N_STAGE(1, 1); N_ALOAD(1, 1);
    N_STAGE(2, 2); N_ALOAD(2, 2);

#define N_STEP(ST, WAITN) do {                                                   \
    asm volatile("s_waitcnt vmcnt(" #WAITN ")" ::: "memory");                    \
    __builtin_amdgcn_s_barrier();                                                \
    asm volatile("" ::: "memory");                                               \
    if ((ST) + 3 < 20) { N_STAGE((ST) + 3, ((ST) + 3) & 3);                      \
                         N_ALOAD((ST) + 3, ((ST) + 3) & 3); }                    \
    _Pragma("unroll")                                                            \
    for (int s_ = 0; s_ < 5; ++s_) {                                             \
        _Pragma("unroll")                                                        \
        for (int f_ = 0; f_ < 2; ++f_) {                                         \
            s16x8 b_ = *(const s16x8*)&Bs[(ST) & 3][(s_ * 2 + f_) * 512 + l * 8];\
            acc[s_][f_][0] = mfma16(A[(ST) & 3][0], b_, acc[s_][f_][0]);         \
            acc[s_][f_][1] = mfma16(A[(ST) & 3][1], b_, acc[s_][f_][1]);         \
        }                                                                        \
    } } while (0)

    N_STEP(0, 10);  N_STEP(1, 10);  N_STEP(2, 10);  N_STEP(3, 10);  N_STEP(4, 10);
    N_STEP(5, 10);  N_STEP(6, 10);  N_STEP(7, 10);  N_STEP(8, 10);  N_STEP(9, 10);
    N_STEP(10, 10); N_STEP(11, 10); N_STEP(12, 10); N_STEP(13, 10); N_STEP(14, 10);
    N_STEP(15, 10); N_STEP(16, 10); N_STEP(17, 10); N_STEP(18, 5);  N_STEP(19, 0);

#undef N_STEP
#undef N_ALOAD
#undef N_STAGE

#pragma unroll
    for (int f = 0; f < 2; ++f) {
        const int col = y * 32 + f * 16 + lane16;
        const bool valid = col < MEM;
        float bff = 0, bi = 0, bo = 0, bu = 0;
        if (valid) {
            bff = b_fioux[col]; bi = b_fioux[300 + col];
            bo = b_fioux[600 + col]; bu = b_fioux[900 + col];
        }
#pragma unroll
        for (int mi = 0; mi < 2; ++mi)
#pragma unroll
            for (int r = 0; r < 4; ++r) {
                int row = w * 32 + mi * 16 + quad * 4 + r;
                size_t hIdx = ((size_t)node * BATCH + row) * NP + col;
                if (valid) {
                    float cl = (float)C[((size_t)li * BATCH + row) * MEM + col];
                    float cr = (float)C[((size_t)ri * BATCH + row) * MEM + col];
                    float ig = sigf(acc[0][f][mi][r] + bi);
                    float og = sigf(acc[1][f][mi][r] + bo);
                    float ug = tanhf_(acc[2][f][mi][r] + bu);
                    float fl = sigf(acc[3][f][mi][r] + bff);
                    float fr = sigf(acc[4][f][mi][r] + bff);
                    float c = ig * ug + fl * cl + fr * cr;
                    float h = og * tanhf_(c);
                    C[((size_t)node * BATCH + row) * MEM + col] = (half_t)c;
                    H[hIdx] = f2bf(h);
                    if (out) {
                        out[row * MEM + col] = c;
                        out[OUT_HALF + row * MEM + col] = h;
                    }
                } else {
                    H[hIdx] = 0;
                }
            }
    }
}

extern "C" void kernel_launch(void* const* d_in, const int* in_sizes, int n_in,
                              void* d_out, int out_size, void* d_ws, size_t ws_size,
                              hipStream_t stream) {
    const float* inputs  = (const float*)d_in[0];
    const float* Wfioux  = (const float*)d_in[1];
    const float* b_fioux = (const float*)d_in[2];
    const float* Wiouh   = (const float*)d_in[3];
    const float* Wfh     = (const float*)d_in[4];
    const int*   left_idx  = (const int*)d_in[5];
    const int*   right_idx = (const int*)d_in[6];

    half_t* C   = (half_t*)d_ws;                              // [1023][128][300] fp16
    short*  H   = (short*)(C + (size_t)NODES * BATCH * MEM);  // [1023][128][320] bf16
    short* WpkN = H + (size_t)NODES * BATCH * NP;             // 2000 frag-blocks
    short* WpkL = WpkN + (size_t)2000 * 512;                  // 600 frag-blocks
    short* X    = WpkL + (size_t)600 * 512;                   // [512][128][320] bf16
    float* out  = (float*)d_out;

    pack_x<<<(LEAVES * BATCH * (NP / 4) + 255) / 256, 256, 0, stream>>>(inputs, X);
    pack_leaf_w<<<150, 256, 0, stream>>>(Wfioux, WpkL);
    pack_node_w<<<500, 256, 0, stream>>>(Wiouh, Wfh, WpkN);

    leaf_mfma<<<dim3(LEAVES, 5), 256, 0, stream>>>(X, WpkL, b_fioux, C, H);

    static const int starts[9] = {512, 768, 896, 960, 992, 1008, 1016, 1020, 1022};
    static const int sizes [9] = {256, 128,  64,  32,  16,    8,    4,    2,    1};
    for (int lvl = 0; lvl < 9; ++lvl) {
        bool root = (lvl == 8);
        node_mfma<<<dim3(sizes[lvl], 10), 256, 0, stream>>>(
            WpkN, b_fioux, left_idx, right_idx, C, H, starts[lvl],
            root ? out : nullptr);
    }
}

// Round 3
// 627.788 us; speedup vs baseline: 1.1240x; 1.0427x over previous
//
#include <hip/hip_runtime.h>
#include <cstdint>

#define BATCH 128
#define NODES 1023
#define LEAVES 512
#define IN_DIM 300
#define MEM 300
#define NP 320              // padded per-set N (and per-child K)
#define OUT_HALF (BATCH*MEM)

typedef __bf16   bf16x8 __attribute__((ext_vector_type(8)));
typedef short    s16x8  __attribute__((ext_vector_type(8)));
typedef short    s16x4  __attribute__((ext_vector_type(4)));
typedef float    f32x4  __attribute__((ext_vector_type(4)));
typedef _Float16 half_t;

__device__ __forceinline__ short f2bf(float f) {
    unsigned u = __float_as_uint(f);
    u += 0x7fff + ((u >> 16) & 1);
    return (short)(u >> 16);
}
__device__ __forceinline__ float sigf(float x)  { return 1.0f / (1.0f + __expf(-x)); }
__device__ __forceinline__ float tanhf_(float x){ return 1.0f - 2.0f / (1.0f + __expf(2.0f * x)); }

__device__ __forceinline__ f32x4 mfma16(s16x8 a, s16x8 b, f32x4 c) {
    return __builtin_amdgcn_mfma_f32_16x16x32_bf16(
        __builtin_bit_cast(bf16x8, a), __builtin_bit_cast(bf16x8, b), c, 0, 0, 0);
}

// async 16B/lane global->LDS: lds dst = wave-uniform base + lane*16
__device__ __forceinline__ void dma16(const short* src, short* ldsBase) {
    __builtin_amdgcn_global_load_lds(
        (const __attribute__((address_space(1))) unsigned int*)src,
        (__attribute__((address_space(3))) unsigned int*)ldsBase,
        16, 0, 0);
}

// ---------- weight packing: B-fragment order ----------
// frag-block (kb,s,nb): 64 lanes x 8 bf16; lane l holds B[k=kb*32+(l>>4)*8+j][n=nb*16+(l&15)]
__global__ __launch_bounds__(256) void pack_node_w(
    const float* __restrict__ Wiouh, const float* __restrict__ Wfh, short* __restrict__ Wpk)
{
    int gid = blockIdx.x * 256 + threadIdx.x;           // 2000 frags * 64 lanes
    if (gid >= 2000 * 64) return;
    int fb = gid >> 6, l = gid & 63;
    int kb = fb / 100, rem = fb % 100, s = rem / 20, nb = rem % 20;
    int n = nb * 16 + (l & 15);
    int kbase = kb * 32 + (l >> 4) * 8;                 // k' in [0,640)
    short v[8];
#pragma unroll
    for (int j = 0; j < 8; ++j) {
        int kp = kbase + j;
        int side = kp >= NP;
        int kk = kp - side * NP;
        float f = 0.0f;
        if (kk < MEM && n < MEM) {
            int k = side * MEM + kk;
            f = (s < 3) ? Wiouh[(size_t)k * 900 + s * 300 + n]
                        : Wfh[(size_t)k * 600 + (s - 3) * 300 + n];
        }
        v[j] = f2bf(f);
    }
    *(s16x8*)&Wpk[(size_t)gid * 8] = *(s16x8*)v;
}

__global__ __launch_bounds__(256) void pack_leaf_w(
    const float* __restrict__ Wfioux, short* __restrict__ Wpk)
{
    int gid = blockIdx.x * 256 + threadIdx.x;           // 600 frags * 64 lanes
    if (gid >= 600 * 64) return;
    int fb = gid >> 6, l = gid & 63;
    int kb = fb / 60, rem = fb % 60, s = rem / 20, nb = rem % 20;
    int n = nb * 16 + (l & 15);
    int kbase = kb * 32 + (l >> 4) * 8;                 // k' in [0,320)
    short v[8];
#pragma unroll
    for (int j = 0; j < 8; ++j) {
        int kp = kbase + j;
        float f = 0.0f;
        if (kp < IN_DIM && n < MEM)
            f = Wfioux[(size_t)kp * 1200 + (s + 1) * 300 + n];
        v[j] = f2bf(f);
    }
    *(s16x8*)&Wpk[(size_t)gid * 8] = *(s16x8*)v;
}

// ---------- leaf-input packing: X[leaf][b][kp] bf16, kp padded to 320 ----------
__global__ __launch_bounds__(256) void pack_x(
    const float* __restrict__ inputs, short* __restrict__ X)
{
    int gid = blockIdx.x * 256 + threadIdx.x;           // 512*128*80 quads
    if (gid >= LEAVES * BATCH * (NP / 4)) return;
    int q = gid % (NP / 4);
    int rb = gid / (NP / 4);
    int b = rb % BATCH, leaf = rb / BATCH;
    short v[4] = {0, 0, 0, 0};
    if (q < IN_DIM / 4) {
        f32x4 f = *(const f32x4*)&inputs[((size_t)b * NODES + leaf) * IN_DIM + q * 4];
        v[0] = f2bf(f[0]); v[1] = f2bf(f[1]); v[2] = f2bf(f[2]); v[3] = f2bf(f[3]);
    }
    *(s16x4*)&X[(size_t)gid * 4] = *(s16x4*)v;
}

// ---------- leaf GEMM+gates: block = 1 leaf x 64-col group ----------
// T3+T4 pipeline: 4-buffer LDS ring, depth-3 prefetch, raw s_barrier with
// counted s_waitcnt vmcnt(N) BEFORE the barrier (never 0 in steady state).
// XCD swizzle: all 5 col-groups of a leaf land on the same XCD (consecutive
// blockIdx round-robins XCDs) so the leaf's X-panel is read once from L3 and
// 4x from that XCD's L2.
__global__ __launch_bounds__(256, 3) void leaf_mfma(
    const short* __restrict__ X, const short* __restrict__ Wpk,
    const float* __restrict__ b_fioux, half_t* __restrict__ C, short* __restrict__ H)
{
    __shared__ short Bs[4][12 * 512];                   // 4 ring bufs x 12 frags x 1KB
    const int t = threadIdx.x;
    const int l = t & 63, w = t >> 6;                   // 4 waves, w = row-group
    const int lane16 = l & 15, quad = l >> 4;

    // bid = (leaf%8) + 8*(y + 5*(leaf/8))  ->  decode:
    const int bid = blockIdx.x;
    const int xcd = bid & 7, tt = bid >> 3;
    const int y = tt % 5;                               // 64-col group 0..4
    const int leaf = (tt / 5) * 8 + xcd;

    const short* Xb = X + (size_t)leaf * BATCH * NP;

    f32x4 acc[3][4][2];                                 // [set][frag][row-half]
#pragma unroll
    for (int s = 0; s < 3; ++s)
#pragma unroll
        for (int f = 0; f < 4; ++f)
#pragma unroll
            for (int mi = 0; mi < 2; ++mi) acc[s][f][mi] = (f32x4)(0.0f);

    s16x8 A[4][2];                                      // A-fragment ring (static idx only)

#define L_STAGE(KB, BUF) do {                                                    \
    _Pragma("unroll")                                                            \
    for (int fl = w; fl < 12; fl += 4) {                                         \
        int s_ = fl >> 2, f_ = fl & 3;                                           \
        const short* src_ = Wpk +                                                \
            ((size_t)(((KB) * 3 + s_) * 20 + y * 4 + f_) * 64 + l) * 8;          \
        dma16(src_, &Bs[BUF][fl * 512]);                                         \
    } } while (0)

#define L_ALOAD(KB, SLOT) do {                                                   \
    const int koff_ = (KB) * 32 + quad * 8;                                      \
    A[SLOT][0] = *(const s16x8*)(Xb + (size_t)(w * 32 + lane16) * NP + koff_);   \
    A[SLOT][1] = *(const s16x8*)(Xb + (size_t)(w * 32 + 16 + lane16) * NP + koff_); \
} while (0)

    // prologue: issue steps 0,1,2 (15 vmem ops per wave in flight)
    L_STAGE(0, 0); L_ALOAD(0, 0);
    L_STAGE(1, 1); L_ALOAD(1, 1);
    L_STAGE(2, 2); L_ALOAD(2, 2);

// waitcnt BEFORE barrier: guarantees every wave's step-ST stage is complete when
// any wave crosses. issue AFTER barrier: ring distance 3 makes the WAR on buffer
// (ST+3)&3 == (ST-1)&3 safe (its readers finished before this barrier).
#define L_STEP(ST, WAITN) do {                                                   \
    asm volatile("s_waitcnt vmcnt(" #WAITN ")" ::: "memory");                    \
    __builtin_amdgcn_s_barrier();                                                \
    asm volatile("" ::: "memory");                                               \
    if ((ST) + 3 < 10) { L_STAGE((ST) + 3, ((ST) + 3) & 3);                      \
                         L_ALOAD((ST) + 3, ((ST) + 3) & 3); }                    \
    _Pragma("unroll")                                                            \
    for (int s_ = 0; s_ < 3; ++s_) {                                             \
        _Pragma("unroll")                                                        \
        for (int f_ = 0; f_ < 4; ++f_) {                                         \
            s16x8 b_ = *(const s16x8*)&Bs[(ST) & 3][(s_ * 4 + f_) * 512 + l * 8];\
            acc[s_][f_][0] = mfma16(A[(ST) & 3][0], b_, acc[s_][f_][0]);         \
            acc[s_][f_][1] = mfma16(A[(ST) & 3][1], b_, acc[s_][f_][1]);         \
        }                                                                        \
    } } while (0)

    L_STEP(0, 10); L_STEP(1, 10); L_STEP(2, 10); L_STEP(3, 10); L_STEP(4, 10);
    L_STEP(5, 10); L_STEP(6, 10); L_STEP(7, 10); L_STEP(8, 5);  L_STEP(9, 0);

#undef L_STEP
#undef L_ALOAD
#undef L_STAGE

#pragma unroll
    for (int f = 0; f < 4; ++f) {
        const int col = y * 64 + f * 16 + lane16;
        const bool valid = col < MEM;
        float bi = 0, bo = 0, bu = 0;
        if (valid) { bi = b_fioux[300 + col]; bo = b_fioux[600 + col]; bu = b_fioux[900 + col]; }
#pragma unroll
        for (int mi = 0; mi < 2; ++mi)
#pragma unroll
            for (int r = 0; r < 4; ++r) {
                int b = w * 32 + mi * 16 + quad * 4 + r;
                size_t hIdx = ((size_t)leaf * BATCH + b) * NP + col;
                if (valid) {
                    float ig = sigf(acc[0][f][mi][r] + bi);
                    float og = sigf(acc[1][f][mi][r] + bo);
                    float ug = tanhf_(acc[2][f][mi][r] + bu);
                    float c = ig * ug;
                    float h = og * tanhf_(c);
                    C[((size_t)leaf * BATCH + b) * MEM + col] = (half_t)c;
                    H[hIdx] = f2bf(h);
                } else {
                    H[hIdx] = 0;
                }
            }
    }
}

// ---------- internal node GEMM+gates: block = 1 node x 32-col group ----------
// Same T3+T4 pipeline, K-step 32 (20 steps over K'=640). Staging padded to 12
// frags/step (slots 10,11 are benign duplicates) so every wave issues exactly
// 3 dma16 + 2 A-loads per step -> uniform compile-time vmcnt counts.
// XCD swizzle (when #nodes % 8 == 0): all 10 col-groups of a node land on the
// same XCD -> child H/C read once from L3, 9x from L2.
__global__ __launch_bounds__(256, 3) void node_mfma(
    const short* __restrict__ Wpk, const float* __restrict__ b_fioux,
    const int* __restrict__ left_idx, const int* __restrict__ right_idx,
    half_t* __restrict__ C, short* __restrict__ H,
    int level_start, int level_size, float* __restrict__ out)
{
    __shared__ short Bs[4][12 * 512];                   // 4 ring bufs x 12KB
    const int t = threadIdx.x;
    const int l = t & 63, w = t >> 6;                   // 4 waves, w = row-group
    const int lane16 = l & 15, quad = l >> 4;

    const int bid = blockIdx.x;
    int nidx, y;
    if ((level_size & 7) == 0) {
        // bid = (n%8) + 8*(y + 10*(n/8))
        const int xcd = bid & 7, tt = bid >> 3;
        y = tt % 10;
        nidx = (tt / 10) * 8 + xcd;
    } else {
        nidx = bid % level_size;
        y = bid / level_size;
    }
    const int node = level_start + nidx;

    const int li = left_idx[node], ri = right_idx[node];
    const short* HL = H + (size_t)li * BATCH * NP;
    const short* HR = H + (size_t)ri * BATCH * NP;

    f32x4 acc[5][2][2];                                 // [set][frag][row-half]
#pragma unroll
    for (int s = 0; s < 5; ++s)
#pragma unroll
        for (int f = 0; f < 2; ++f)
#pragma unroll
            for (int mi = 0; mi < 2; ++mi) acc[s][f][mi] = (f32x4)(0.0f);

    s16x8 A[4][2];

#define N_STAGE(KB, BUF) do {                                                    \
    _Pragma("unroll")                                                            \
    for (int fl = w; fl < 12; fl += 4) {                                         \
        int rfl_ = (fl < 10) ? fl : fl - 10;            /* slots 10,11: dup */   \
        int s_ = rfl_ >> 1, f_ = rfl_ & 1;                                       \
        const short* src_ = Wpk +                                                \
            ((size_t)(((KB) * 5 + s_) * 20 + y * 2 + f_) * 64 + l) * 8;          \
        dma16(src_, &Bs[BUF][fl * 512]);                                         \
    } } while (0)

#define N_ALOAD(KB, SLOT) do {                                                   \
    const short* Hb_ = (((KB) >= 10) ? HR : HL) +                                \
                       ((KB) - (((KB) >= 10) ? 10 : 0)) * 32 + quad * 8;         \
    A[SLOT][0] = *(const s16x8*)(Hb_ + (size_t)(w * 32 + lane16) * NP);          \
    A[SLOT][1] = *(const s16x8*)(Hb_ + (size_t)(w * 32 + 16 + lane16) * NP);     \
} while (0)

    N_STAGE(0, 0); N_ALOAD(0, 0);
    N_STAGE(1, 1); N_ALOAD(1, 1);
    N_STAGE(2, 2); N_ALOAD(2, 2);

#define N_STEP(ST, WAITN) do {                                                   \
    asm volatile("s_waitcnt vmcnt(" #WAITN ")" ::: "memory");                    \
    __builtin_amdgcn_s_barrier();                                                \
    asm volatile("" ::: "memory");                                               \
    if ((ST) + 3 < 20) { N_STAGE((ST) + 3, ((ST) + 3) & 3);                      \
                         N_ALOAD((ST) + 3, ((ST) + 3) & 3); }                    \
    _Pragma("unroll")                                                            \
    for (int s_ = 0; s_ < 5; ++s_) {                                             \
        _Pragma("unroll")                                                        \
        for (int f_ = 0; f_ < 2; ++f_) {                                         \
            s16x8 b_ = *(const s16x8*)&Bs[(ST) & 3][(s_ * 2 + f_) * 512 + l * 8];\
            acc[s_][f_][0] = mfma16(A[(ST) & 3][0], b_, acc[s_][f_][0]);         \
            acc[s_][f_][1] = mfma16(A[(ST) & 3][1], b_, acc[s_][f_][1]);         \
        }                                                                        \
    } } while (0)

    N_STEP(0, 10);  N_STEP(1, 10);  N_STEP(2, 10);  N_STEP(3, 10);  N_STEP(4, 10);
    N_STEP(5, 10);  N_STEP(6, 10);  N_STEP(7, 10);  N_STEP(8, 10);  N_STEP(9, 10);
    N_STEP(10, 10); N_STEP(11, 10); N_STEP(12, 10); N_STEP(13, 10); N_STEP(14, 10);
    N_STEP(15, 10); N_STEP(16, 10); N_STEP(17, 10); N_STEP(18, 5);  N_STEP(19, 0);

#undef N_STEP
#undef N_ALOAD
#undef N_STAGE

#pragma unroll
    for (int f = 0; f < 2; ++f) {
        const int col = y * 32 + f * 16 + lane16;
        const bool valid = col < MEM;
        float bff = 0, bi = 0, bo = 0, bu = 0;
        if (valid) {
            bff = b_fioux[col]; bi = b_fioux[300 + col];
            bo = b_fioux[600 + col]; bu = b_fioux[900 + col];
        }
#pragma unroll
        for (int mi = 0; mi < 2; ++mi)
#pragma unroll
            for (int r = 0; r < 4; ++r) {
                int row = w * 32 + mi * 16 + quad * 4 + r;
                size_t hIdx = ((size_t)node * BATCH + row) * NP + col;
                if (valid) {
                    float cl = (float)C[((size_t)li * BATCH + row) * MEM + col];
                    float cr = (float)C[((size_t)ri * BATCH + row) * MEM + col];
                    float ig = sigf(acc[0][f][mi][r] + bi);
                    float og = sigf(acc[1][f][mi][r] + bo);
                    float ug = tanhf_(acc[2][f][mi][r] + bu);
                    float fl = sigf(acc[3][f][mi][r] + bff);
                    float fr = sigf(acc[4][f][mi][r] + bff);
                    float c = ig * ug + fl * cl + fr * cr;
                    float h = og * tanhf_(c);
                    C[((size_t)node * BATCH + row) * MEM + col] = (half_t)c;
                    H[hIdx] = f2bf(h);
                    if (out) {
                        out[row * MEM + col] = c;
                        out[OUT_HALF + row * MEM + col] = h;
                    }
                } else {
                    H[hIdx] = 0;
                }
            }
    }
}

extern "C" void kernel_launch(void* const* d_in, const int* in_sizes, int n_in,
                              void* d_out, int out_size, void* d_ws, size_t ws_size,
                              hipStream_t stream) {
    const float* inputs  = (const float*)d_in[0];
    const float* Wfioux  = (const float*)d_in[1];
    const float* b_fioux = (const float*)d_in[2];
    const float* Wiouh   = (const float*)d_in[3];
    const float* Wfh     = (const float*)d_in[4];
    const int*   left_idx  = (const int*)d_in[5];
    const int*   right_idx = (const int*)d_in[6];

    half_t* C   = (half_t*)d_ws;                              // [1023][128][300] fp16
    short*  H   = (short*)(C + (size_t)NODES * BATCH * MEM);  // [1023][128][320] bf16
    short* WpkN = H + (size_t)NODES * BATCH * NP;             // 2000 frag-blocks
    short* WpkL = WpkN + (size_t)2000 * 512;                  // 600 frag-blocks
    short* X    = WpkL + (size_t)600 * 512;                   // [512][128][320] bf16
    float* out  = (float*)d_out;

    pack_x<<<(LEAVES * BATCH * (NP / 4) + 255) / 256, 256, 0, stream>>>(inputs, X);
    pack_leaf_w<<<150, 256, 0, stream>>>(Wfioux, WpkL);
    pack_node_w<<<500, 256, 0, stream>>>(Wiouh, Wfh, WpkN);

    leaf_mfma<<<LEAVES * 5, 256, 0, stream>>>(X, WpkL, b_fioux, C, H);

    static const int starts[9] = {512, 768, 896, 960, 992, 1008, 1016, 1020, 1022};
    static const int sizes [9] = {256, 128,  64,  32,  16,    8,    4,    2,    1};
    for (int lvl = 0; lvl < 9; ++lvl) {
        bool root = (lvl == 8);
        node_mfma<<<sizes[lvl] * 10, 256, 0, stream>>>(
            WpkN, b_fioux, left_idx, right_idx, C, H, starts[lvl], sizes[lvl],
            root ? out : nullptr);
    }
}